// Round 1
// 735.945 us; speedup vs baseline: 1.0234x; 1.0234x over previous
//
#include <hip/hip_runtime.h>
#include <cmath>

namespace {
constexpr int KD = 256;   // k_max
constexpr int PD = 256;   // p_max
constexpr int SD = 10;    // num_samples
constexpr float EPSF = 1e-9f;
typedef __attribute__((ext_vector_type(4))) float f4;
}

__device__ __forceinline__ float wave_max64(float v) {
#pragma unroll
  for (int off = 32; off > 0; off >>= 1)
    v = fmaxf(v, __shfl_xor(v, off, 64));
  return v;
}

// compare-exchange, descending (v[i] >= v[j]); no NaNs by construction
#define CSWAP(i, j)                 \
  {                                 \
    float hi = fmaxf(v[i], v[j]);   \
    float lo = fminf(v[i], v[j]);   \
    v[i] = hi;                      \
    v[j] = lo;                      \
  }

// Load 8 rows x 4 cols of P into a register buffer (8 KB/wave in flight).
// Nontemporal: the 512 MB P stream is touch-once; don't pollute L2.
#define LOAD_CHUNK(kk, buf)                                                   \
  {                                                                           \
    _Pragma("unroll") for (int j = 0; j < 8; ++j) {                           \
      f4 t = __builtin_nontemporal_load(                                      \
          (const f4*)(Pb + (size_t)((kk) + j) * PD + p0));                    \
      buf[j][0] = t[0]; buf[j][1] = t[1]; buf[j][2] = t[2]; buf[j][3] = t[3]; \
    }                                                                         \
  }

// 320 FMAs against LDS-broadcast X for one 8-row chunk.
#define COMPUTE_CHUNK(kk, buf)                                                \
  {                                                                           \
    _Pragma("unroll") for (int s = 0; s < SD; ++s) {                          \
      f4 x0 = *(const f4*)&Xl[s * KD + (kk)];                                 \
      f4 x1 = *(const f4*)&Xl[s * KD + (kk) + 4];                             \
      float xv[8] = {x0[0], x0[1], x0[2], x0[3], x1[0], x1[1], x1[2], x1[3]}; \
      _Pragma("unroll") for (int j = 0; j < 8; ++j)                           \
        _Pragma("unroll") for (int r = 0; r < 4; ++r)                         \
          acc[s][r] = fmaf(xv[j], buf[j][r], acc[s][r]);                      \
    }                                                                         \
  }

__global__ __launch_bounds__(64) void vil_main(
    const float* __restrict__ y_pred, const float* __restrict__ y_true,
    const float* __restrict__ Pmat, const float* __restrict__ params,
    const float* __restrict__ Xs, float* __restrict__ accum,
    float* __restrict__ out, float invB) {
  const int b = blockIdx.x;
  const int lane = threadIdx.x;

  __shared__ float Xl[SD * KD];

  // stage X[b] (S*K = 2560 floats) into LDS, coalesced float4
  {
    const f4* src = (const f4*)(Xs + (size_t)b * SD * KD);
    f4* dst = (f4*)Xl;
#pragma unroll
    for (int i = 0; i < (SD * KD / 4) / 64; ++i)  // 10 iters
      dst[i * 64 + lane] = src[i * 64 + lane];
  }
  __syncthreads();

  const int n  = (int)params[3 * b + 0];
  const int kb = (int)params[3 * b + 1];
  const int m  = (int)params[3 * b + 2];
  const int nk = n - kb;  // valid columns of the product half

  float acc[SD][4];
#pragma unroll
  for (int s = 0; s < SD; ++s)
#pragma unroll
    for (int r = 0; r < 4; ++r) acc[s][r] = 0.0f;

  const int p0 = lane * 4;  // this lane's 4 product columns
  const float* __restrict__ Pb = Pmat + (size_t)b * KD * PD;

  if (p0 < nk) {  // lanes fully past n-k issue no P loads: BW saving
    // Double-buffered register prefetch: loads for chunk i+1 are in flight
    // while chunk i is FMA'd -> partial vmcnt waits, no per-chunk stall.
    const int kb16 = kb & ~15;
    float bufA[8][4], bufB[8][4];
    if (kb16 >= 16) {
      LOAD_CHUNK(0, bufA)
      for (int kk = 0; kk < kb16; kk += 16) {
        LOAD_CHUNK(kk + 8, bufB)
        COMPUTE_CHUNK(kk, bufA)
        if (kk + 16 < kb16) LOAD_CHUNK(kk + 16, bufA)
        COMPUTE_CHUNK(kk + 8, bufB)
      }
    }
    // generality tail (kb % 16 != 0); unused for this data (kb = 256)
    for (int kk = kb16; kk < kb; ++kk) {
      const float* pr = Pb + (size_t)kk * PD + p0;
#pragma unroll
      for (int s = 0; s < SD; ++s) {
        float xv = Xl[s * KD + kk];
#pragma unroll
        for (int r = 0; r < 4; ++r) acc[s][r] = fmaf(xv, pr[r], acc[s][r]);
      }
    }
  }

  // ---- selection: per sample, top-(m+1) of 512 masked |C| values ----
  // FULLY unrolled over s so every acc[s][r] index is compile-time constant
  // (runtime-indexed register arrays demote to scratch -- rule #20).
  float maxhm = -3.0e38f;
#pragma unroll
  for (int s = 0; s < SD; ++s) {
    float v[8];
    // first half: columns j = lane + 64q hold Xm[s][j] (valid iff j < kb)
#pragma unroll
    for (int q = 0; q < 4; ++q) {
      int j = lane + 64 * q;
      v[q] = (j < kb) ? fabsf(Xl[s * KD + j]) : -1.0f;
    }
    // second half: columns K + p0 + r (valid iff p0+r < nk)
#pragma unroll
    for (int r = 0; r < 4; ++r)
      v[4 + r] = (p0 + r < nk) ? fabsf(acc[s][r]) : -1.0f;

    // Batcher odd-even mergesort, 8 elements, descending (19 comparators)
    CSWAP(0,1) CSWAP(2,3) CSWAP(4,5) CSWAP(6,7)
    CSWAP(0,2) CSWAP(1,3) CSWAP(4,6) CSWAP(5,7)
    CSWAP(1,2) CSWAP(5,6)
    CSWAP(0,4) CSWAP(1,5) CSWAP(2,6) CSWAP(3,7)
    CSWAP(2,4) CSWAP(3,5)
    CSWAP(1,2) CSWAP(3,4) CSWAP(5,6)

    float cmax = 0.0f, cm = 0.0f;
    for (int t = 0;; ++t) {        // m is wave-uniform; <= 9 iterations
      float g = wave_max64(v[0]);  // global max of remaining values
      if (t == 0) cmax = g;
      if (t == m) { cm = g; break; }
      // remove exactly one instance of g (tie-safe, matches sort semantics)
      unsigned long long mk = __ballot(v[0] == g);
      int owner = __ffsll(mk) - 1;
      if (lane == owner) {
        v[0] = v[1]; v[1] = v[2]; v[2] = v[3]; v[3] = v[4];
        v[4] = v[5]; v[5] = v[6]; v[6] = v[7]; v[7] = -2.0f;
      }
    }
    float hm = cmax / (cm + EPSF);
    maxhm = fmaxf(maxhm, hm);
  }

  // ---- per-block contribution + folded finalization (no second kernel) ----
  if (lane == 0) {
    float pen = ((m + 1) <= n) ? fmaxf(maxhm - y_pred[b], 0.0f) : 0.0f;
    atomicAdd(&accum[1], pen);
    float lp = log2f(fmaxf(y_pred[b], EPSF));
    float lt = log2f(fmaxf(y_true[b], EPSF));
    float d = lt - lp;
    atomicAdd(&accum[0], d * d);

    __threadfence();  // release our accum adds before announcing done
    unsigned int prev = atomicAdd((unsigned int*)(accum + 2), 1u);
    if (prev == gridDim.x - 1) {  // last block to finish finalizes
      __threadfence();            // acquire all other blocks' adds
      float s0 = atomicAdd(&accum[0], 0.0f);  // coherent read via atomic
      float s1 = atomicAdd(&accum[1], 0.0f);
      float logmse = s0 * invB;
      float viol = s1 * invB;
      out[0] = fmaf(0.5f, viol, logmse);  // total_loss
      out[1] = logmse;                    // loss_logmse
      out[2] = viol;                      // loss_violation
    }
  }
}

extern "C" void kernel_launch(void* const* d_in, const int* in_sizes, int n_in,
                              void* d_out, int out_size, void* d_ws, size_t ws_size,
                              hipStream_t stream) {
  const float* y_pred = (const float*)d_in[0];
  const float* y_true = (const float*)d_in[1];
  const float* Pmat   = (const float*)d_in[2];
  const float* params = (const float*)d_in[3];
  const float* Xs     = (const float*)d_in[4];
  float* out = (float*)d_out;
  float* accum = (float*)d_ws;  // [0]=sum d^2, [1]=sum pen, [2]=done counter
  const int B = in_sizes[0];

  hipMemsetAsync(accum, 0, 3 * sizeof(float), stream);
  vil_main<<<dim3(B), dim3(64), 0, stream>>>(y_pred, y_true, Pmat, params, Xs,
                                             accum, out, 1.0f / (float)B);
}